// Round 6
// baseline (320.898 us; speedup 1.0000x reference)
//
#include <hip/hip_runtime.h>
#include <stdint.h>

typedef __bf16 bf16;
typedef __bf16 bf16x2 __attribute__((ext_vector_type(2)));
typedef __bf16 bf16x4 __attribute__((ext_vector_type(4)));
typedef __bf16 bf16x8 __attribute__((ext_vector_type(8)));
typedef float f32x4 __attribute__((ext_vector_type(4)));
typedef float f32x16 __attribute__((ext_vector_type(16)));
typedef uint32_t u32;
typedef unsigned int u32x2 __attribute__((ext_vector_type(2)));

#define QSCALE 0.1803368801111137f   /* 0.125 * log2(e) */

__device__ __forceinline__ float fast_exp2(float x) {
#if __has_builtin(__builtin_amdgcn_exp2f)
  return __builtin_amdgcn_exp2f(x);
#else
  return exp2f(x);
#endif
}

__device__ __forceinline__ float fast_rcp(float x) {
#if __has_builtin(__builtin_amdgcn_rcpf)
  return __builtin_amdgcn_rcpf(x);
#else
  return 1.0f / x;
#endif
}

// gelu(v) = 0.5 v (1 + erf(v/sqrt2)); erf via A&S 7.1.25 (|err|<=2.5e-5).
__device__ __forceinline__ float fast_gelu(float v) {
  float u = v * 0.70710678118654752f;
  float a = __builtin_fabsf(u);
  float t = fast_rcp(__builtin_fmaf(0.47047f, a, 1.0f));
  float e = fast_exp2(-a * a * 1.4426950408889634f);
  float poly = ((0.7478556f * t - 0.0958798f) * t + 0.3480242f) * t;
  float erf_abs = __builtin_fmaf(-poly, e, 1.0f);
  float erf = __builtin_copysignf(erf_abs, u);
  return 0.5f * v * (1.0f + erf);
}

__device__ __forceinline__ u32 pack_bf16(float a, float b) {
  bf16x2 v; v[0] = (bf16)a; v[1] = (bf16)b;
  return __builtin_bit_cast(u32, v);
}

// v_permlane32_swap_b32: post-op a[l<32]=a_old[l], a[l>=32]=b_old[l-32];
//                        b[l<32]=a_old[l+32],  b[l>=32]=b_old[l]
__device__ __forceinline__ void permswap32(u32& a, u32& b) {
#if __has_builtin(__builtin_amdgcn_permlane32_swap)
  u32x2 r = __builtin_amdgcn_permlane32_swap(a, b, false, false);
  a = r[0]; b = r[1];
#else
  asm volatile("v_permlane32_swap_b32 %0, %1" : "+v"(a), "+v"(b));
#endif
}

// async global->LDS, 16B per lane; LDS dest = wave-uniform base + lane*16
__device__ __forceinline__ void async16(void* lds, const void* g) {
  __builtin_amdgcn_global_load_lds(
      (__attribute__((address_space(1))) uint32_t*)(uintptr_t)g,
      (__attribute__((address_space(3))) uint32_t*)(uint32_t)(uintptr_t)lds,
      16, 0, 0);
}

// ---------------- fused prep: LN1 + all weight conversions + bias ----------------
__device__ __forceinline__ void transpose_body(
    const float* __restrict__ in, bf16* __restrict__ outp, int R, int C,
    int bx, int by, float (*tile)[33], int t)
{
  int bc = bx * 32, br = by * 32;
  int tc = t & 31, tr = t >> 5;
  #pragma unroll
  for (int i = 0; i < 4; i++)
    tile[tr + i * 8][tc] = in[(size_t)(br + tr + i * 8) * C + bc + tc];
  __syncthreads();
  #pragma unroll
  for (int i = 0; i < 4; i++) {
    int c = bc + tr + i * 8;
    outp[(size_t)c * R + br + tc] = (bf16)tile[tc][tr + i * 8];
  }
}

__global__ __launch_bounds__(256) void prep_kernel(
    const float* __restrict__ x,
    const float* __restrict__ ln1w, const float* __restrict__ ln1b,
    const float* __restrict__ Wq, const float* __restrict__ Wk,
    const float* __restrict__ Wv,
    const float* __restrict__ Wo, const float* __restrict__ W1,
    const float* __restrict__ W2,
    const float* __restrict__ bq, const float* __restrict__ bk,
    const float* __restrict__ bv,
    bf16* __restrict__ ybuf, bf16* __restrict__ Wqkv_t,
    bf16* __restrict__ Wo_t, bf16* __restrict__ W1_t, bf16* __restrict__ W2_t,
    float* __restrict__ bqkv)
{
  __shared__ float tile[32][33];
  int n = blockIdx.x;
  int t = threadIdx.x;
  if (n < 4096) {
    int row = n;
    const float* xr = x + (size_t)row * 768;
    float v0 = xr[t], v1 = xr[t + 256], v2 = xr[t + 512];
    float s = v0 + v1 + v2, s2 = v0 * v0 + v1 * v1 + v2 * v2;
    #pragma unroll
    for (int d = 1; d < 64; d <<= 1) {
      s  += __shfl_xor(s, d, 64);
      s2 += __shfl_xor(s2, d, 64);
    }
    float* red = &tile[0][0];
    int wv = t >> 6, ln = t & 63;
    if (ln == 0) { red[wv] = s; red[4 + wv] = s2; }
    __syncthreads();
    s  = red[0] + red[1] + red[2] + red[3];
    s2 = red[4] + red[5] + red[6] + red[7];
    float mu = s * (1.0f / 768.0f);
    float var = s2 * (1.0f / 768.0f) - mu * mu;
    float rstd = rsqrtf(var + 1e-5f);
    bf16* yr = ybuf + (size_t)row * 768;
    yr[t]       = (bf16)((v0 - mu) * rstd * ln1w[t]       + ln1b[t]);
    yr[t + 256] = (bf16)((v1 - mu) * rstd * ln1w[t + 256] + ln1b[t + 256]);
    yr[t + 512] = (bf16)((v2 - mu) * rstd * ln1w[t + 512] + ln1b[t + 512]);
  } else if (n < 5824) {
    int n2 = n - 4096;
    int bz = n2 / 48, rem = n2 - bz * 48;
    int by = rem / 24, bx = rem - by * 24;
    int part = bz / 12, h = bz - part * 12;
    const float* W = (part == 0) ? Wq : (part == 1) ? Wk : Wv;
    float sc = (part == 0) ? QSCALE : 1.0f;
    int bd = bx * 32, be = by * 32;
    int tc = t & 31, tr = t >> 5;
    #pragma unroll
    for (int i = 0; i < 4; i++)
      tile[tr + i * 8][tc] = W[((size_t)h * 768 + bd + tr + i * 8) * 64 + be + tc] * sc;
    __syncthreads();
    #pragma unroll
    for (int i = 0; i < 4; i++) {
      int e = be + tr + i * 8;
      Wqkv_t[(size_t)(part * 768 + h * 64 + e) * 768 + bd + tc] = (bf16)tile[tc][tr + i * 8];
    }
  } else if (n < 6400) {
    int m = n - 5824;
    transpose_body(Wo, Wo_t, 768, 768, m % 24, m / 24, tile, t);
  } else if (n < 8704) {
    int m = n - 6400;
    transpose_body(W1, W1_t, 768, 3072, m % 96, m / 96, tile, t);
  } else if (n < 11008) {
    int m = n - 8704;
    transpose_body(W2, W2_t, 3072, 768, m % 24, m / 24, tile, t);
  } else {
    int idx = (n - 11008) * 256 + t;   // [0,2304)
    int part = idx / 768, nn = idx - part * 768;
    const float* B = (part == 0) ? bq : (part == 1) ? bk : bv;
    float v = B[nn];
    if (part == 0) v *= QSCALE;
    bqkv[idx] = v;
  }
}

// out[i] += (float)p[i]; grid 3072 x 256 over 4096*768
__global__ __launch_bounds__(256) void reduce_add_kernel(
    float* __restrict__ out, const bf16* __restrict__ p)
{
  int i = blockIdx.x * 256 + threadIdx.x;
  float4 o = ((float4*)out)[i];
  bf16x4 v = ((const bf16x4*)p)[i];
  o.x += (float)v[0]; o.y += (float)v[1];
  o.z += (float)v[2]; o.w += (float)v[3];
  ((float4*)out)[i] = o;
}

// fused: x1 += (float)p; y = LN(x1)
__global__ __launch_bounds__(256) void ln_add_kernel(
    float* __restrict__ x1, const bf16* __restrict__ p,
    const float* __restrict__ w, const float* __restrict__ b,
    bf16* __restrict__ y)
{
  int row = blockIdx.x;
  float* xr = x1 + (size_t)row * 768;
  const bf16* pr = p + (size_t)row * 768;
  int t = threadIdx.x;
  float v0 = xr[t]       + (float)pr[t];
  float v1 = xr[t + 256] + (float)pr[t + 256];
  float v2 = xr[t + 512] + (float)pr[t + 512];
  xr[t] = v0; xr[t + 256] = v1; xr[t + 512] = v2;
  float s = v0 + v1 + v2, s2 = v0 * v0 + v1 * v1 + v2 * v2;
  #pragma unroll
  for (int d = 1; d < 64; d <<= 1) {
    s  += __shfl_xor(s, d, 64);
    s2 += __shfl_xor(s2, d, 64);
  }
  __shared__ float red[8];
  int wv = t >> 6, ln = t & 63;
  if (ln == 0) { red[wv] = s; red[4 + wv] = s2; }
  __syncthreads();
  s  = red[0] + red[1] + red[2] + red[3];
  s2 = red[4] + red[5] + red[6] + red[7];
  float mu = s * (1.0f / 768.0f);
  float var = s2 * (1.0f / 768.0f) - mu * mu;
  float rstd = rsqrtf(var + 1e-5f);
  bf16* yr = y + (size_t)row * 768;
  yr[t]       = (bf16)((v0 - mu) * rstd * w[t]       + b[t]);
  yr[t + 256] = (bf16)((v1 - mu) * rstd * w[t + 256] + b[t + 256]);
  yr[t + 512] = (bf16)((v2 - mu) * rstd * w[t + 512] + b[t + 512]);
}

// ---------------- GEMM: C = A[M][K] * Bt[N][K]^T ----------------
// Single-barrier double-buffered pipeline. Template BN = N-tile (128 or 64):
// BN=64 doubles the grid for the same work/partials — fixes the 1.5-2.25
// blocks/CU starvation of the small-N GEMMs (Wo/FFN2/QKV) without the
// split-K partial-traffic cost that regressed in round 4.
// MODE 2: out bf16 = gelu(acc + bias)   (fast erf)
// MODE 4: QKV split: col<1536 -> qk[row][col]; else V^T: out2[(col-1536)*4096+row]
// MODE 5: split-K x NZ: z=0 -> f32 outp = res+acc+bias; z>=1 -> bf16 partial
template <int MODE, int BN>
__global__ __launch_bounds__(256) void gemm_bt(
    const bf16* __restrict__ A, const bf16* __restrict__ Bt,
    const float* __restrict__ bias, const float* __restrict__ res,
    void* __restrict__ outp, void* __restrict__ out2, int M, int N, int K)
{
  constexpr int NBT = BN / 32;           // 16-wide n-subtiles per wave
  __shared__ bf16 As[2 * 128 * 32];
  __shared__ bf16 Bs[2 * BN * 32];
  int t = threadIdx.x;
  int w = t >> 6, lane = t & 63;
  int quad = lane >> 4, l16 = lane & 15;
  int tile_m = blockIdx.y * 128, tile_n = blockIdx.x * BN;

  int srow = lane >> 2;
  int skb = (lane & 3) * 8;
  const bf16* Ag = A  + (size_t)(tile_m + w * 16 + srow) * K + skb;
  const bf16* Bg = Bt + (size_t)(tile_n + w * 16 + srow) * K + skb;
  char* AsB = (char*)As + w * 1024;
  char* BsB = (char*)Bs + w * 1024;
  size_t rstep = (size_t)64 * K;

  int wm = (w >> 1) * 64, wn = (w & 1) * (BN / 2);
  f32x4 acc[4][NBT] = {};

  int kbeg = 0, kend = K;
  if (MODE == 5) {
    int slice = K / (int)gridDim.z;
    kbeg = blockIdx.z * slice;
    kend = kbeg + slice;
  }

  // prologue: stage first tile into buffer 0
  async16(AsB,        Ag + kbeg);
  async16(AsB + 4096, Ag + rstep + kbeg);
  async16(BsB,        Bg + kbeg);
  if (BN == 128) async16(BsB + 4096, Bg + rstep + kbeg);

  int cur = 0;
  for (int k0 = kbeg; k0 < kend; k0 += 32) {
    __syncthreads();   // drains stage(cur) [issued last iter]; prev reads done
    if (k0 + 32 < kend) {
      char* An = AsB + (cur ^ 1) * 8192;
      char* Bn = BsB + (cur ^ 1) * (BN * 64);
      async16(An,        Ag + k0 + 32);
      async16(An + 4096, Ag + rstep + k0 + 32);
      async16(Bn,        Bg + k0 + 32);
      if (BN == 128) async16(Bn + 4096, Bg + rstep + k0 + 32);
    }
    const bf16* Ab = As + cur * 4096;
    const bf16* Bb = Bs + cur * (BN * 32);

    bf16x8 af[4], bfr[NBT];
    #pragma unroll
    for (int mb = 0; mb < 4; mb++)
      af[mb] = *(const bf16x8*)(Ab + (wm + mb * 16 + l16) * 32 + quad * 8);
    #pragma unroll
    for (int nb = 0; nb < NBT; nb++)
      bfr[nb] = *(const bf16x8*)(Bb + (wn + nb * 16 + l16) * 32 + quad * 8);
    #pragma unroll
    for (int mb = 0; mb < 4; mb++)
      #pragma unroll
      for (int nb = 0; nb < NBT; nb++)
        acc[mb][nb] = __builtin_amdgcn_mfma_f32_16x16x32_bf16(
            af[mb], bfr[nb], acc[mb][nb], 0, 0, 0);
    cur ^= 1;
  }

  #pragma unroll
  for (int mb = 0; mb < 4; mb++) {
    #pragma unroll
    for (int nb = 0; nb < NBT; nb++) {
      int col = tile_n + wn + nb * 16 + l16;
      int row0 = tile_m + wm + mb * 16 + quad * 4;
      if (MODE == 4) {
        float bc = bias[col];
        if (col < 1536) {
          #pragma unroll
          for (int r = 0; r < 4; r++)
            ((bf16*)outp)[(size_t)(row0 + r) * 1536 + col] =
                (bf16)(acc[mb][nb][r] + bc);
        } else {
          bf16x4 pk;
          #pragma unroll
          for (int r = 0; r < 4; r++) pk[r] = (bf16)(acc[mb][nb][r] + bc);
          *(bf16x4*)((bf16*)out2 + (size_t)(col - 1536) * 4096 + row0) = pk;
        }
      } else if (MODE == 2) {
        float bc = bias[col];
        #pragma unroll
        for (int r = 0; r < 4; r++) {
          size_t idx = (size_t)(row0 + r) * N + col;
          ((bf16*)outp)[idx] = (bf16)fast_gelu(acc[mb][nb][r] + bc);
        }
      } else {  // MODE 5
        if (blockIdx.z == 0) {
          float bc = bias[col];
          #pragma unroll
          for (int r = 0; r < 4; r++) {
            size_t idx = (size_t)(row0 + r) * N + col;
            ((float*)outp)[idx] = res[idx] + acc[mb][nb][r] + bc;
          }
        } else {
          size_t pbase = (size_t)(blockIdx.z - 1) * M * N;
          #pragma unroll
          for (int r = 0; r < 4; r++) {
            size_t idx = (size_t)(row0 + r) * N + col;
            ((bf16*)out2)[pbase + idx] = (bf16)acc[mb][nb][r];
          }
        }
      }
    }
  }
}

// ---------------- flash attention v7 (reverted from v8; measured 79.0) ----------
// permlane32_swap P-fragment build + tree-reduced exp sum + setprio around
// MFMA clusters. Q=128/block, 32x32x16 MFMA, waves 2x2, kv-split x2, 48KB LDS.
__global__ __launch_bounds__(256) void flash_kernel(
    const bf16* __restrict__ qk, const bf16* __restrict__ vtg,
    bf16* __restrict__ Opart, float* __restrict__ Lpart)
{
  __shared__ char smem[49152];
  bf16* Qs = (bf16*)smem;   // [128 q][64 hd] 16KB; K dbuf @16384+cur*8192; V @32768+cur*8192
  int t = threadIdx.x, w = t >> 6, lane = t & 63;
  int l32 = lane & 31, hi = lane >> 5;
  int qt = blockIdx.x, h = blockIdx.y, z = blockIdx.z;
  int q0 = qt * 128, kv0 = z * 2048;
  int qsel = w & 1, ksel = w >> 1;
  int qw = qsel * 64, kb = ksel * 32;

  int srow = lane >> 3, scol = ((lane & 7) ^ srow) * 8;

  // stage Q (4 rounds x 32 rows)
  #pragma unroll
  for (int c = 0; c < 4; c++) {
    const bf16* qg = qk + (size_t)(q0 + c * 32 + w * 8 + srow) * 1536 + h * 64 + scol;
    async16(smem + c * 4096 + w * 1024, qg);
  }

  const bf16* kg = qk + 768 + h * 64 + (size_t)(kv0 + w * 8 + srow) * 1536 + scol;
  const bf16* vg = vtg + (size_t)(h * 64 + w * 8 + srow) * 4096 + kv0 + scol;

  { // K/V tile 0 -> buffer 0
    char* kb0 = smem + 16384 + w * 1024;
    char* vb0 = smem + 32768 + w * 1024;
    async16(kb0,        kg);
    async16(kb0 + 4096, kg + (size_t)32 * 1536);
    async16(vb0,        vg);
    async16(vb0 + 4096, vg + (size_t)32 * 4096);
  }
  __syncthreads();

  // hoist Q fragments for both q-subtiles (B-operand [q][hd])
  int qr0 = qw + l32, qr1 = qw + 32 + l32;
  bf16x8 qf0[4], qf1[4];
  #pragma unroll
  for (int ks = 0; ks < 4; ks++) {
    qf0[ks] = *(const bf16x8*)(Qs + qr0 * 64 + (((ks * 2 + hi) ^ (qr0 & 7)) * 8));
    qf1[ks] = *(const bf16x8*)(Qs + qr1 * 64 + (((ks * 2 + hi) ^ (qr1 & 7)) * 8));
  }

  f32x16 oT00 = {}, oT10 = {}, oT01 = {}, oT11 = {};  // [e-half][q-subtile]
  float l0 = 0.0f, l1 = 0.0f;
  int krow = kb + l32;
  int er0 = l32, er1 = 32 + l32;

  for (int j = 0; j < 32; j++) {
    int cur = j & 1;
    if (j < 31) {   // prefetch tile j+1 into the other buffer
      const bf16* kgn = kg + (size_t)(j + 1) * 64 * 1536;
      const bf16* vgn = vg + (j + 1) * 64;
      char* kbn = smem + 16384 + (cur ^ 1) * 8192 + w * 1024;
      char* vbn = smem + 32768 + (cur ^ 1) * 8192 + w * 1024;
      async16(kbn,        kgn);
      async16(kbn + 4096, kgn + (size_t)32 * 1536);
      async16(vbn,        vgn);
      async16(vbn + 4096, vgn + (size_t)32 * 4096);
    }
    const bf16* Ks = (const bf16*)(smem + 16384 + cur * 8192);
    const bf16* Vs = (const bf16*)(smem + 32768 + cur * 8192);

    // S^T = K Q^T over hd=64 for both q-subtiles (K frags shared)
    f32x16 s0 = {}, s1 = {};
    __builtin_amdgcn_s_setprio(1);
    #pragma unroll
    for (int ks = 0; ks < 4; ks++) {
      bf16x8 kf = *(const bf16x8*)(Ks + krow * 64 + (((ks * 2 + hi) ^ (krow & 7)) * 8));
      s0 = __builtin_amdgcn_mfma_f32_32x32x16_bf16(kf, qf0[ks], s0, 0, 0, 0);
      s1 = __builtin_amdgcn_mfma_f32_32x32x16_bf16(kf, qf1[ks], s1, 0, 0, 0);
    }
    __builtin_amdgcn_s_setprio(0);

    // no-max softmax + in-register P^T fragment build (permlane32_swap)
    bf16x8 pf00, pf01, pf10, pf11;
    {
      float p[16];
      #pragma unroll
      for (int i = 0; i < 16; i++) p[i] = fast_exp2(s0[i]);
      float t0 = (p[0] + p[1]) + (p[2] + p[3]);
      float t1 = (p[4] + p[5]) + (p[6] + p[7]);
      float t2 = (p[8] + p[9]) + (p[10] + p[11]);
      float t3 = (p[12] + p[13]) + (p[14] + p[15]);
      l0 += (t0 + t1) + (t2 + t3);
      u32 dd[8];
      #pragma unroll
      for (int k = 0; k < 8; k++) dd[k] = pack_bf16(p[2 * k], p[2 * k + 1]);
      permswap32(dd[0], dd[2]);
      permswap32(dd[1], dd[3]);
      permswap32(dd[4], dd[6]);
      permswap32(dd[5], dd[7]);
      pf00 = __builtin_bit_cast(bf16x8, uint4{dd[0], dd[1], dd[2], dd[3]});
      pf01 = __builtin_bit_cast(bf16x8, uint4{dd[4], dd[5], dd[6], dd[7]});
    }
    {
      float p[16];
      #pragma unroll
      for (int i = 0; i < 16; i++) p[i] = fast_exp2(s1[i]);
      float t0 = (p[0] + p[1]) + (p[2] + p[3]);
      float t1 = (p[4] + p[5]) + (p[6] + p[7]);
      float t2 = (p[8] + p[9]) + (p[10] + p[11]);
      float t3 = (p[12] + p[13]) + (p[14] + p[15]);
      l1 += (t0 + t1) + (t2 + t3);
      u32 dd[8];
      #pragma unroll
      for (int k = 0; k < 8; k++) dd[k] = pack_bf16(p[2 * k], p[2 * k + 1]);
      permswap32(dd[0], dd[2]);
      permswap32(dd[1], dd[3]);
      permswap32(dd[4], dd[6]);
      permswap32(dd[5], dd[7]);
      pf10 = __builtin_bit_cast(bf16x8, uint4{dd[0], dd[1], dd[2], dd[3]});
      pf11 = __builtin_bit_cast(bf16x8, uint4{dd[4], dd[5], dd[6], dd[7]});
    }

    // O^T += V^T P^T (V frags shared across q-subtiles)
    __builtin_amdgcn_s_setprio(1);
    #pragma unroll
    for (int kstep = 0; kstep < 2; kstep++) {
      int grp = (kb >> 3) + kstep * 2 + hi;
      bf16x8 va = *(const bf16x8*)(Vs + er0 * 64 + ((grp ^ (er0 & 7)) * 8));
      bf16x8 vb = *(const bf16x8*)(Vs + er1 * 64 + ((grp ^ (er1 & 7)) * 8));
      bf16x8 pa = kstep ? pf01 : pf00;
      bf16x8 pb = kstep ? pf11 : pf10;
      oT00 = __builtin_amdgcn_mfma_f32_32x32x16_bf16(va, pa, oT00, 0, 0, 0);
      oT10 = __builtin_amdgcn_mfma_f32_32x32x16_bf16(vb, pa, oT10, 0, 0, 0);
      oT01 = __builtin_amdgcn_mfma_f32_32x32x16_bf16(va, pb, oT01, 0, 0, 0);
      oT11 = __builtin_amdgcn_mfma_f32_32x32x16_bf16(vb, pb, oT11, 0, 0, 0);
    }
    __builtin_amdgcn_s_setprio(0);

    __syncthreads();   // drains j+1 loads (hidden under this iter's compute)
  }

  // cross-ksel combine via LDS; OS stride 67 f32 (coprime 32 -> conflict-free)
  float lq0 = l0 + __shfl_xor(l0, 32, 64);
  float lq1 = l1 + __shfl_xor(l1, 32, 64);
  float* OS = (float*)smem;            // [128 q][67] f32 = 34304 B
  float* LS = (float*)(smem + 34304);  // [128 q] f32
  if (ksel == 1) {
    #pragma unroll
    for (int i = 0; i < 16; i++) {
      int eoff = (i & 3) + 8 * (i >> 2) + 4 * hi;
      OS[qr0 * 67 + eoff]      = oT00[i];
      OS[qr0 * 67 + 32 + eoff] = oT10[i];
      OS[qr1 * 67 + eoff]      = oT01[i];
      OS[qr1 * 67 + 32 + eoff] = oT11[i];
    }
    if (hi == 0) { LS[qr0] = lq0; LS[qr1] = lq1; }
  }
  __syncthreads();
  if (ksel == 0) {
    size_t tb = ((size_t)z * 12 + h) * 32 + qt;
    float la0 = lq0 + LS[qr0], la1 = lq1 + LS[qr1];
    if (hi == 0) { Lpart[tb * 128 + qr0] = la0; Lpart[tb * 128 + qr1] = la1; }
    bf16* ob0 = Opart + tb * 8192 + (size_t)qr0 * 64;
    bf16* ob1 = Opart + tb * 8192 + (size_t)qr1 * 64;
    #pragma unroll
    for (int g = 0; g < 4; g++) {
      int e0 = 8 * g + 4 * hi;
      bf16x4 a0, a1, b0, b1;
      #pragma unroll
      for (int r = 0; r < 4; r++) {
        a0[r] = (bf16)(oT00[g * 4 + r] + OS[qr0 * 67 + e0 + r]);
        a1[r] = (bf16)(oT10[g * 4 + r] + OS[qr0 * 67 + 32 + e0 + r]);
        b0[r] = (bf16)(oT01[g * 4 + r] + OS[qr1 * 67 + e0 + r]);
        b1[r] = (bf16)(oT11[g * 4 + r] + OS[qr1 * 67 + 32 + e0 + r]);
      }
      *(bf16x4*)(ob0 + e0)      = a0;
      *(bf16x4*)(ob0 + 32 + e0) = a1;
      *(bf16x4*)(ob1 + e0)      = b0;
      *(bf16x4*)(ob1 + 32 + e0) = b1;
    }
  }
}

// combine kv-split partials: o = (O0+O1)/(l0+l1); grid (32 qt, 12 h)
__global__ __launch_bounds__(256) void flash_combine_kernel(
    const bf16* __restrict__ Opart, const float* __restrict__ Lpart,
    bf16* __restrict__ o)
{
  int qt = blockIdx.x, h = blockIdx.y;
  int t = threadIdx.x;
  size_t t0 = (size_t)h * 32 + qt;
  size_t t1 = (size_t)(12 + h) * 32 + qt;
  #pragma unroll
  for (int qq = 0; qq < 2; qq++) {
    int q = qq * 64 + (t >> 2), eg = (t & 3) * 16;
    float inv = 1.0f / (Lpart[t0 * 128 + q] + Lpart[t1 * 128 + q]);
    const bf16* p0 = Opart + t0 * 8192 + (size_t)q * 64 + eg;
    const bf16* p1 = Opart + t1 * 8192 + (size_t)q * 64 + eg;
    bf16x8 a0 = *(const bf16x8*)p0, a1 = *(const bf16x8*)(p0 + 8);
    bf16x8 b0 = *(const bf16x8*)p1, b1 = *(const bf16x8*)(p1 + 8);
    bf16x8 r0, r1;
    #pragma unroll
    for (int i = 0; i < 8; i++) {
      r0[i] = (bf16)(((float)a0[i] + (float)b0[i]) * inv);
      r1[i] = (bf16)(((float)a1[i] + (float)b1[i]) * inv);
    }
    bf16* op = o + (size_t)(qt * 128 + q) * 768 + h * 64 + eg;
    *(bf16x8*)op       = r0;
    *(bf16x8*)(op + 8) = r1;
  }
}

extern "C" void kernel_launch(void* const* d_in, const int* in_sizes, int n_in,
                              void* d_out, int out_size, void* d_ws, size_t ws_size,
                              hipStream_t stream) {
  const float* x    = (const float*)d_in[0];
  const float* Wq   = (const float*)d_in[1];
  const float* bq   = (const float*)d_in[2];
  const float* Wk   = (const float*)d_in[3];
  const float* bk   = (const float*)d_in[4];
  const float* Wv   = (const float*)d_in[5];
  const float* bv   = (const float*)d_in[6];
  const float* Wo   = (const float*)d_in[7];
  const float* bo   = (const float*)d_in[8];
  const float* ln1w = (const float*)d_in[9];
  const float* ln1b = (const float*)d_in[10];
  const float* ln2w = (const float*)d_in[11];
  const float* ln2b = (const float*)d_in[12];
  const float* W1   = (const float*)d_in[13];
  const float* b1   = (const float*)d_in[14];
  const float* W2   = (const float*)d_in[15];
  const float* b2   = (const float*)d_in[16];
  float* out = (float*)d_out;

  // workspace layout (58,205,184 B):
  //  0         .. 25165824 : hbuf [4096][3072] bf16 (FFN1 out)
  //                          earlier: Lpart(0..393216) / ybuf(0..6291456, ln1)
  //                          qkbuf(6291456..18874368) / vtg(18874368..25165824)
  //                          opar_o(6291456..12582912, O-proj z=1 partial)
  //  25165824  .. 37748736 : x1 f32 [4096][768]; earlier Opart bf16 [2*12*32][128][64]
  //  37748736  .. 44040192 : obuf/y2buf bf16 [4096][768]; later FFN2 z=1 partial
  //  44040192  .. 58195968 : Wqkv_t | Wo_t | W1_t | W2_t (bf16)
  //  58195968  .. 58205184 : bqkv f32 [2304]
  char* ws = (char*)d_ws;
  bf16*  hbuf   = (bf16*)(ws + 0);
  float* Lpart  = (float*)(ws + 0);
  bf16*  ybuf   = (bf16*)(ws + 0);
  bf16*  qkbuf  = (bf16*)(ws + 6291456);
  bf16*  opar_o = (bf16*)(ws + 6291456);
  bf16*  vtg    = (bf16*)(ws + 18874368);
  float* x1     = (float*)(ws + 25165824);
  bf16*  Opart  = (bf16*)(ws + 25165824);
  bf16*  obuf   = (bf16*)(ws + 37748736);
  bf16*  y2buf  = obuf;
  bf16*  opar_f = obuf;                      // FFN2 z=1 partial (y2 dead)
  bf16*  Wqkv_t = (bf16*)(ws + 44040192);
  bf16*  Wo_t   = (bf16*)(ws + 47579136);
  bf16*  W1_t   = (bf16*)(ws + 48758784);
  bf16*  W2_t   = (bf16*)(ws + 53477376);
  float* bqkv   = (float*)(ws + 58195968);

  // 0) fused prep: LN1 + all weight conversions + qkv bias
  prep_kernel<<<11017, 256, 0, stream>>>(x, ln1w, ln1b, Wq, Wk, Wv, Wo, W1, W2,
                                         bq, bk, bv,
                                         ybuf, Wqkv_t, Wo_t, W1_t, W2_t, bqkv);
  // 2) qk | v^T = y @ Wqkv + bqkv   (BN=64: 1152 blocks = 4.5/CU, was 2.25)
  gemm_bt<4, 64><<<dim3(36, 32), 256, 0, stream>>>(ybuf, Wqkv_t, bqkv,
                                                   (const float*)nullptr, qkbuf, vtg,
                                                   4096, 2304, 768);
  // 3) flash attention partials + combine -> obuf [4096][768]
  flash_kernel<<<dim3(32, 12, 2), 256, 0, stream>>>(qkbuf, vtg, Opart, Lpart);
  flash_combine_kernel<<<dim3(32, 12), 256, 0, stream>>>(Opart, Lpart, obuf);
  // 4) x1 = x + obuf @ Wo + bo  (BN=64 + split-K x2: 768 blocks = 3/CU)
  gemm_bt<5, 64><<<dim3(12, 32, 2), 256, 0, stream>>>(obuf, Wo_t, bo, x, x1, opar_o,
                                                      4096, 768, 768);
  // 5) x1 += opar_o; y2 = LN2(x1)   (fused)
  ln_add_kernel<<<4096, 256, 0, stream>>>(x1, opar_o, ln2w, ln2b, y2buf);
  // 6) h = gelu(y2 @ W1 + b1)   (BN=128: already 3/CU exact)
  gemm_bt<2, 128><<<dim3(24, 32), 256, 0, stream>>>(y2buf, W1_t, b1,
                                                    (const float*)nullptr, hbuf, nullptr,
                                                    4096, 3072, 768);
  // 7) out = x1 + h @ W2 + b2  (BN=64 + split-K x2: 768 blocks = 3/CU)
  gemm_bt<5, 64><<<dim3(12, 32, 2), 256, 0, stream>>>(hbuf, W2_t, b2, x1, out, opar_f,
                                                      4096, 768, 3072);
  reduce_add_kernel<<<3072, 256, 0, stream>>>(out, opar_f);
}

// Round 7
// 299.485 us; speedup vs baseline: 1.0715x; 1.0715x over previous
//
#include <hip/hip_runtime.h>
#include <stdint.h>

typedef __bf16 bf16;
typedef __bf16 bf16x2 __attribute__((ext_vector_type(2)));
typedef __bf16 bf16x4 __attribute__((ext_vector_type(4)));
typedef __bf16 bf16x8 __attribute__((ext_vector_type(8)));
typedef float f32x4 __attribute__((ext_vector_type(4)));
typedef float f32x16 __attribute__((ext_vector_type(16)));
typedef uint32_t u32;
typedef unsigned int u32x2 __attribute__((ext_vector_type(2)));

#define QSCALE 0.1803368801111137f   /* 0.125 * log2(e) */

__device__ __forceinline__ float fast_exp2(float x) {
#if __has_builtin(__builtin_amdgcn_exp2f)
  return __builtin_amdgcn_exp2f(x);
#else
  return exp2f(x);
#endif
}

__device__ __forceinline__ float fast_rcp(float x) {
#if __has_builtin(__builtin_amdgcn_rcpf)
  return __builtin_amdgcn_rcpf(x);
#else
  return 1.0f / x;
#endif
}

// gelu(v) = 0.5 v (1 + erf(v/sqrt2)); erf via A&S 7.1.25 (|err|<=2.5e-5).
__device__ __forceinline__ float fast_gelu(float v) {
  float u = v * 0.70710678118654752f;
  float a = __builtin_fabsf(u);
  float t = fast_rcp(__builtin_fmaf(0.47047f, a, 1.0f));
  float e = fast_exp2(-a * a * 1.4426950408889634f);
  float poly = ((0.7478556f * t - 0.0958798f) * t + 0.3480242f) * t;
  float erf_abs = __builtin_fmaf(-poly, e, 1.0f);
  float erf = __builtin_copysignf(erf_abs, u);
  return 0.5f * v * (1.0f + erf);
}

__device__ __forceinline__ u32 pack_bf16(float a, float b) {
  bf16x2 v; v[0] = (bf16)a; v[1] = (bf16)b;
  return __builtin_bit_cast(u32, v);
}

// v_permlane32_swap_b32: post-op a[l<32]=a_old[l], a[l>=32]=b_old[l-32];
//                        b[l<32]=a_old[l+32],  b[l>=32]=b_old[l]
__device__ __forceinline__ void permswap32(u32& a, u32& b) {
#if __has_builtin(__builtin_amdgcn_permlane32_swap)
  u32x2 r = __builtin_amdgcn_permlane32_swap(a, b, false, false);
  a = r[0]; b = r[1];
#else
  asm volatile("v_permlane32_swap_b32 %0, %1" : "+v"(a), "+v"(b));
#endif
}

// async global->LDS, 16B per lane; LDS dest = wave-uniform base + lane*16
__device__ __forceinline__ void async16(void* lds, const void* g) {
  __builtin_amdgcn_global_load_lds(
      (__attribute__((address_space(1))) uint32_t*)(uintptr_t)g,
      (__attribute__((address_space(3))) uint32_t*)(uint32_t)(uintptr_t)lds,
      16, 0, 0);
}

// ---------------- fused prep: LN1 + all weight conversions + bias ----------------
__device__ __forceinline__ void transpose_body(
    const float* __restrict__ in, bf16* __restrict__ outp, int R, int C,
    int bx, int by, float (*tile)[33], int t)
{
  int bc = bx * 32, br = by * 32;
  int tc = t & 31, tr = t >> 5;
  #pragma unroll
  for (int i = 0; i < 4; i++)
    tile[tr + i * 8][tc] = in[(size_t)(br + tr + i * 8) * C + bc + tc];
  __syncthreads();
  #pragma unroll
  for (int i = 0; i < 4; i++) {
    int c = bc + tr + i * 8;
    outp[(size_t)c * R + br + tc] = (bf16)tile[tc][tr + i * 8];
  }
}

__global__ __launch_bounds__(256) void prep_kernel(
    const float* __restrict__ x,
    const float* __restrict__ ln1w, const float* __restrict__ ln1b,
    const float* __restrict__ Wq, const float* __restrict__ Wk,
    const float* __restrict__ Wv,
    const float* __restrict__ Wo, const float* __restrict__ W1,
    const float* __restrict__ W2,
    const float* __restrict__ bq, const float* __restrict__ bk,
    const float* __restrict__ bv,
    bf16* __restrict__ ybuf, bf16* __restrict__ Wqkv_t,
    bf16* __restrict__ Wo_t, bf16* __restrict__ W1_t, bf16* __restrict__ W2_t,
    float* __restrict__ bqkv)
{
  __shared__ float tile[32][33];
  int n = blockIdx.x;
  int t = threadIdx.x;
  if (n < 4096) {
    int row = n;
    const float* xr = x + (size_t)row * 768;
    float v0 = xr[t], v1 = xr[t + 256], v2 = xr[t + 512];
    float s = v0 + v1 + v2, s2 = v0 * v0 + v1 * v1 + v2 * v2;
    #pragma unroll
    for (int d = 1; d < 64; d <<= 1) {
      s  += __shfl_xor(s, d, 64);
      s2 += __shfl_xor(s2, d, 64);
    }
    float* red = &tile[0][0];
    int wv = t >> 6, ln = t & 63;
    if (ln == 0) { red[wv] = s; red[4 + wv] = s2; }
    __syncthreads();
    s  = red[0] + red[1] + red[2] + red[3];
    s2 = red[4] + red[5] + red[6] + red[7];
    float mu = s * (1.0f / 768.0f);
    float var = s2 * (1.0f / 768.0f) - mu * mu;
    float rstd = rsqrtf(var + 1e-5f);
    bf16* yr = ybuf + (size_t)row * 768;
    yr[t]       = (bf16)((v0 - mu) * rstd * ln1w[t]       + ln1b[t]);
    yr[t + 256] = (bf16)((v1 - mu) * rstd * ln1w[t + 256] + ln1b[t + 256]);
    yr[t + 512] = (bf16)((v2 - mu) * rstd * ln1w[t + 512] + ln1b[t + 512]);
  } else if (n < 5824) {
    int n2 = n - 4096;
    int bz = n2 / 48, rem = n2 - bz * 48;
    int by = rem / 24, bx = rem - by * 24;
    int part = bz / 12, h = bz - part * 12;
    const float* W = (part == 0) ? Wq : (part == 1) ? Wk : Wv;
    float sc = (part == 0) ? QSCALE : 1.0f;
    int bd = bx * 32, be = by * 32;
    int tc = t & 31, tr = t >> 5;
    #pragma unroll
    for (int i = 0; i < 4; i++)
      tile[tr + i * 8][tc] = W[((size_t)h * 768 + bd + tr + i * 8) * 64 + be + tc] * sc;
    __syncthreads();
    #pragma unroll
    for (int i = 0; i < 4; i++) {
      int e = be + tr + i * 8;
      Wqkv_t[(size_t)(part * 768 + h * 64 + e) * 768 + bd + tc] = (bf16)tile[tc][tr + i * 8];
    }
  } else if (n < 6400) {
    int m = n - 5824;
    transpose_body(Wo, Wo_t, 768, 768, m % 24, m / 24, tile, t);
  } else if (n < 8704) {
    int m = n - 6400;
    transpose_body(W1, W1_t, 768, 3072, m % 96, m / 96, tile, t);
  } else if (n < 11008) {
    int m = n - 8704;
    transpose_body(W2, W2_t, 3072, 768, m % 24, m / 24, tile, t);
  } else {
    int idx = (n - 11008) * 256 + t;   // [0,2304)
    int part = idx / 768, nn = idx - part * 768;
    const float* B = (part == 0) ? bq : (part == 1) ? bk : bv;
    float v = B[nn];
    if (part == 0) v *= QSCALE;
    bqkv[idx] = v;
  }
}

// out[i] += (float)p[i]; grid 3072 x 256 over 4096*768
__global__ __launch_bounds__(256) void reduce_add_kernel(
    float* __restrict__ out, const bf16* __restrict__ p)
{
  int i = blockIdx.x * 256 + threadIdx.x;
  float4 o = ((float4*)out)[i];
  bf16x4 v = ((const bf16x4*)p)[i];
  o.x += (float)v[0]; o.y += (float)v[1];
  o.z += (float)v[2]; o.w += (float)v[3];
  ((float4*)out)[i] = o;
}

// fused: x1 += (float)p; y = LN(x1)
__global__ __launch_bounds__(256) void ln_add_kernel(
    float* __restrict__ x1, const bf16* __restrict__ p,
    const float* __restrict__ w, const float* __restrict__ b,
    bf16* __restrict__ y)
{
  int row = blockIdx.x;
  float* xr = x1 + (size_t)row * 768;
  const bf16* pr = p + (size_t)row * 768;
  int t = threadIdx.x;
  float v0 = xr[t]       + (float)pr[t];
  float v1 = xr[t + 256] + (float)pr[t + 256];
  float v2 = xr[t + 512] + (float)pr[t + 512];
  xr[t] = v0; xr[t + 256] = v1; xr[t + 512] = v2;
  float s = v0 + v1 + v2, s2 = v0 * v0 + v1 * v1 + v2 * v2;
  #pragma unroll
  for (int d = 1; d < 64; d <<= 1) {
    s  += __shfl_xor(s, d, 64);
    s2 += __shfl_xor(s2, d, 64);
  }
  __shared__ float red[8];
  int wv = t >> 6, ln = t & 63;
  if (ln == 0) { red[wv] = s; red[4 + wv] = s2; }
  __syncthreads();
  s  = red[0] + red[1] + red[2] + red[3];
  s2 = red[4] + red[5] + red[6] + red[7];
  float mu = s * (1.0f / 768.0f);
  float var = s2 * (1.0f / 768.0f) - mu * mu;
  float rstd = rsqrtf(var + 1e-5f);
  bf16* yr = y + (size_t)row * 768;
  yr[t]       = (bf16)((v0 - mu) * rstd * w[t]       + b[t]);
  yr[t + 256] = (bf16)((v1 - mu) * rstd * w[t + 256] + b[t + 256]);
  yr[t + 512] = (bf16)((v2 - mu) * rstd * w[t + 512] + b[t + 512]);
}

// ---------------- GEMM: C = A[M][K] * Bt[N][K]^T (round-3 config + T1) ----------
// Single-barrier double-buffered pipeline, 128x128 tile.
// T1 XCD-aware chunked swizzle: dispatch order round-robins XCDs; remap the
// flattened block id so each XCD gets a CONTIGUOUS run of tiles (consecutive
// tiles share the A row-panel -> panel stays in that XCD's 4MB L2).
// Requires gridDim.x*gridDim.y % 8 == 0 (576/192/768 all qualify).
// MODE 2: out bf16 = gelu(acc + bias)   (fast erf)
// MODE 4: QKV split: col<1536 -> qk[row][col]; else V^T: out2[(col-1536)*4096+row]
// MODE 5: split-K x NZ: z=0 -> f32 outp = res+acc+bias; z>=1 -> bf16 partial
template <int MODE>
__global__ __launch_bounds__(256) void gemm_bt(
    const bf16* __restrict__ A, const bf16* __restrict__ Bt,
    const float* __restrict__ bias, const float* __restrict__ res,
    void* __restrict__ outp, void* __restrict__ out2, int M, int N, int K)
{
  __shared__ bf16 As[2 * 128 * 32];
  __shared__ bf16 Bs[2 * 128 * 32];
  int t = threadIdx.x;
  int w = t >> 6, lane = t & 63;
  int quad = lane >> 4, l16 = lane & 15;

  // T1 chunked XCD swizzle (bijective: nwg % 8 == 0 for all our grids)
  int nwg = gridDim.x * gridDim.y;
  int id = blockIdx.y * gridDim.x + blockIdx.x;
  int cpx = nwg >> 3;
  int swz = (id & 7) * cpx + (id >> 3);
  int tile_n = (swz % gridDim.x) * 128;
  int tile_m = (swz / gridDim.x) * 128;

  int srow = lane >> 2;
  int skb = (lane & 3) * 8;
  const bf16* Ag = A  + (size_t)(tile_m + w * 16 + srow) * K + skb;
  const bf16* Bg = Bt + (size_t)(tile_n + w * 16 + srow) * K + skb;
  char* AsB = (char*)As + w * 1024;
  char* BsB = (char*)Bs + w * 1024;
  size_t rstep = (size_t)64 * K;

  int wm = (w >> 1) * 64, wn = (w & 1) * 64;
  f32x4 acc[4][4] = {};

  int kbeg = 0, kend = K;
  if (MODE == 5) {
    int slice = K / (int)gridDim.z;
    kbeg = blockIdx.z * slice;
    kend = kbeg + slice;
  }

  // prologue: stage first tile into buffer 0
  async16(AsB,        Ag + kbeg);
  async16(AsB + 4096, Ag + rstep + kbeg);
  async16(BsB,        Bg + kbeg);
  async16(BsB + 4096, Bg + rstep + kbeg);

  int cur = 0;
  for (int k0 = kbeg; k0 < kend; k0 += 32) {
    __syncthreads();   // drains stage(cur) [issued last iter]; prev reads done
    if (k0 + 32 < kend) {
      char* An = AsB + (cur ^ 1) * 8192;
      char* Bn = BsB + (cur ^ 1) * 8192;
      async16(An,        Ag + k0 + 32);
      async16(An + 4096, Ag + rstep + k0 + 32);
      async16(Bn,        Bg + k0 + 32);
      async16(Bn + 4096, Bg + rstep + k0 + 32);
    }
    const bf16* Ab = As + cur * 4096;
    const bf16* Bb = Bs + cur * 4096;

    bf16x8 af[4], bfr[4];
    #pragma unroll
    for (int mb = 0; mb < 4; mb++)
      af[mb] = *(const bf16x8*)(Ab + (wm + mb * 16 + l16) * 32 + quad * 8);
    #pragma unroll
    for (int nb = 0; nb < 4; nb++)
      bfr[nb] = *(const bf16x8*)(Bb + (wn + nb * 16 + l16) * 32 + quad * 8);
    #pragma unroll
    for (int mb = 0; mb < 4; mb++)
      #pragma unroll
      for (int nb = 0; nb < 4; nb++)
        acc[mb][nb] = __builtin_amdgcn_mfma_f32_16x16x32_bf16(
            af[mb], bfr[nb], acc[mb][nb], 0, 0, 0);
    cur ^= 1;
  }

  #pragma unroll
  for (int mb = 0; mb < 4; mb++) {
    #pragma unroll
    for (int nb = 0; nb < 4; nb++) {
      int col = tile_n + wn + nb * 16 + l16;
      int row0 = tile_m + wm + mb * 16 + quad * 4;
      if (MODE == 4) {
        float bc = bias[col];
        if (col < 1536) {
          #pragma unroll
          for (int r = 0; r < 4; r++)
            ((bf16*)outp)[(size_t)(row0 + r) * 1536 + col] =
                (bf16)(acc[mb][nb][r] + bc);
        } else {
          bf16x4 pk;
          #pragma unroll
          for (int r = 0; r < 4; r++) pk[r] = (bf16)(acc[mb][nb][r] + bc);
          *(bf16x4*)((bf16*)out2 + (size_t)(col - 1536) * 4096 + row0) = pk;
        }
      } else if (MODE == 2) {
        float bc = bias[col];
        #pragma unroll
        for (int r = 0; r < 4; r++) {
          size_t idx = (size_t)(row0 + r) * N + col;
          ((bf16*)outp)[idx] = (bf16)fast_gelu(acc[mb][nb][r] + bc);
        }
      } else {  // MODE 5
        if (blockIdx.z == 0) {
          float bc = bias[col];
          #pragma unroll
          for (int r = 0; r < 4; r++) {
            size_t idx = (size_t)(row0 + r) * N + col;
            ((float*)outp)[idx] = res[idx] + acc[mb][nb][r] + bc;
          }
        } else {
          size_t pbase = (size_t)(blockIdx.z - 1) * M * N;
          #pragma unroll
          for (int r = 0; r < 4; r++) {
            size_t idx = (size_t)(row0 + r) * N + col;
            ((bf16*)out2)[pbase + idx] = (bf16)acc[mb][nb][r];
          }
        }
      }
    }
  }
}

// ---------------- flash attention v7 (measured 78.4-79.2; unchanged control) -----
// permlane32_swap P-fragment build + tree-reduced exp sum + setprio around
// MFMA clusters. Q=128/block, 32x32x16 MFMA, waves 2x2, kv-split x2, 48KB LDS.
__global__ __launch_bounds__(256) void flash_kernel(
    const bf16* __restrict__ qk, const bf16* __restrict__ vtg,
    bf16* __restrict__ Opart, float* __restrict__ Lpart)
{
  __shared__ char smem[49152];
  bf16* Qs = (bf16*)smem;   // [128 q][64 hd] 16KB; K dbuf @16384+cur*8192; V @32768+cur*8192
  int t = threadIdx.x, w = t >> 6, lane = t & 63;
  int l32 = lane & 31, hi = lane >> 5;
  int qt = blockIdx.x, h = blockIdx.y, z = blockIdx.z;
  int q0 = qt * 128, kv0 = z * 2048;
  int qsel = w & 1, ksel = w >> 1;
  int qw = qsel * 64, kb = ksel * 32;

  int srow = lane >> 3, scol = ((lane & 7) ^ srow) * 8;

  // stage Q (4 rounds x 32 rows)
  #pragma unroll
  for (int c = 0; c < 4; c++) {
    const bf16* qg = qk + (size_t)(q0 + c * 32 + w * 8 + srow) * 1536 + h * 64 + scol;
    async16(smem + c * 4096 + w * 1024, qg);
  }

  const bf16* kg = qk + 768 + h * 64 + (size_t)(kv0 + w * 8 + srow) * 1536 + scol;
  const bf16* vg = vtg + (size_t)(h * 64 + w * 8 + srow) * 4096 + kv0 + scol;

  { // K/V tile 0 -> buffer 0
    char* kb0 = smem + 16384 + w * 1024;
    char* vb0 = smem + 32768 + w * 1024;
    async16(kb0,        kg);
    async16(kb0 + 4096, kg + (size_t)32 * 1536);
    async16(vb0,        vg);
    async16(vb0 + 4096, vg + (size_t)32 * 4096);
  }
  __syncthreads();

  // hoist Q fragments for both q-subtiles (B-operand [q][hd])
  int qr0 = qw + l32, qr1 = qw + 32 + l32;
  bf16x8 qf0[4], qf1[4];
  #pragma unroll
  for (int ks = 0; ks < 4; ks++) {
    qf0[ks] = *(const bf16x8*)(Qs + qr0 * 64 + (((ks * 2 + hi) ^ (qr0 & 7)) * 8));
    qf1[ks] = *(const bf16x8*)(Qs + qr1 * 64 + (((ks * 2 + hi) ^ (qr1 & 7)) * 8));
  }

  f32x16 oT00 = {}, oT10 = {}, oT01 = {}, oT11 = {};  // [e-half][q-subtile]
  float l0 = 0.0f, l1 = 0.0f;
  int krow = kb + l32;
  int er0 = l32, er1 = 32 + l32;

  for (int j = 0; j < 32; j++) {
    int cur = j & 1;
    if (j < 31) {   // prefetch tile j+1 into the other buffer
      const bf16* kgn = kg + (size_t)(j + 1) * 64 * 1536;
      const bf16* vgn = vg + (j + 1) * 64;
      char* kbn = smem + 16384 + (cur ^ 1) * 8192 + w * 1024;
      char* vbn = smem + 32768 + (cur ^ 1) * 8192 + w * 1024;
      async16(kbn,        kgn);
      async16(kbn + 4096, kgn + (size_t)32 * 1536);
      async16(vbn,        vgn);
      async16(vbn + 4096, vgn + (size_t)32 * 4096);
    }
    const bf16* Ks = (const bf16*)(smem + 16384 + cur * 8192);
    const bf16* Vs = (const bf16*)(smem + 32768 + cur * 8192);

    // S^T = K Q^T over hd=64 for both q-subtiles (K frags shared)
    f32x16 s0 = {}, s1 = {};
    __builtin_amdgcn_s_setprio(1);
    #pragma unroll
    for (int ks = 0; ks < 4; ks++) {
      bf16x8 kf = *(const bf16x8*)(Ks + krow * 64 + (((ks * 2 + hi) ^ (krow & 7)) * 8));
      s0 = __builtin_amdgcn_mfma_f32_32x32x16_bf16(kf, qf0[ks], s0, 0, 0, 0);
      s1 = __builtin_amdgcn_mfma_f32_32x32x16_bf16(kf, qf1[ks], s1, 0, 0, 0);
    }
    __builtin_amdgcn_s_setprio(0);

    // no-max softmax + in-register P^T fragment build (permlane32_swap)
    bf16x8 pf00, pf01, pf10, pf11;
    {
      float p[16];
      #pragma unroll
      for (int i = 0; i < 16; i++) p[i] = fast_exp2(s0[i]);
      float t0 = (p[0] + p[1]) + (p[2] + p[3]);
      float t1 = (p[4] + p[5]) + (p[6] + p[7]);
      float t2 = (p[8] + p[9]) + (p[10] + p[11]);
      float t3 = (p[12] + p[13]) + (p[14] + p[15]);
      l0 += (t0 + t1) + (t2 + t3);
      u32 dd[8];
      #pragma unroll
      for (int k = 0; k < 8; k++) dd[k] = pack_bf16(p[2 * k], p[2 * k + 1]);
      permswap32(dd[0], dd[2]);
      permswap32(dd[1], dd[3]);
      permswap32(dd[4], dd[6]);
      permswap32(dd[5], dd[7]);
      pf00 = __builtin_bit_cast(bf16x8, uint4{dd[0], dd[1], dd[2], dd[3]});
      pf01 = __builtin_bit_cast(bf16x8, uint4{dd[4], dd[5], dd[6], dd[7]});
    }
    {
      float p[16];
      #pragma unroll
      for (int i = 0; i < 16; i++) p[i] = fast_exp2(s1[i]);
      float t0 = (p[0] + p[1]) + (p[2] + p[3]);
      float t1 = (p[4] + p[5]) + (p[6] + p[7]);
      float t2 = (p[8] + p[9]) + (p[10] + p[11]);
      float t3 = (p[12] + p[13]) + (p[14] + p[15]);
      l1 += (t0 + t1) + (t2 + t3);
      u32 dd[8];
      #pragma unroll
      for (int k = 0; k < 8; k++) dd[k] = pack_bf16(p[2 * k], p[2 * k + 1]);
      permswap32(dd[0], dd[2]);
      permswap32(dd[1], dd[3]);
      permswap32(dd[4], dd[6]);
      permswap32(dd[5], dd[7]);
      pf10 = __builtin_bit_cast(bf16x8, uint4{dd[0], dd[1], dd[2], dd[3]});
      pf11 = __builtin_bit_cast(bf16x8, uint4{dd[4], dd[5], dd[6], dd[7]});
    }

    // O^T += V^T P^T (V frags shared across q-subtiles)
    __builtin_amdgcn_s_setprio(1);
    #pragma unroll
    for (int kstep = 0; kstep < 2; kstep++) {
      int grp = (kb >> 3) + kstep * 2 + hi;
      bf16x8 va = *(const bf16x8*)(Vs + er0 * 64 + ((grp ^ (er0 & 7)) * 8));
      bf16x8 vb = *(const bf16x8*)(Vs + er1 * 64 + ((grp ^ (er1 & 7)) * 8));
      bf16x8 pa = kstep ? pf01 : pf00;
      bf16x8 pb = kstep ? pf11 : pf10;
      oT00 = __builtin_amdgcn_mfma_f32_32x32x16_bf16(va, pa, oT00, 0, 0, 0);
      oT10 = __builtin_amdgcn_mfma_f32_32x32x16_bf16(vb, pa, oT10, 0, 0, 0);
      oT01 = __builtin_amdgcn_mfma_f32_32x32x16_bf16(va, pb, oT01, 0, 0, 0);
      oT11 = __builtin_amdgcn_mfma_f32_32x32x16_bf16(vb, pb, oT11, 0, 0, 0);
    }
    __builtin_amdgcn_s_setprio(0);

    __syncthreads();   // drains j+1 loads (hidden under this iter's compute)
  }

  // cross-ksel combine via LDS; OS stride 67 f32 (coprime 32 -> conflict-free)
  float lq0 = l0 + __shfl_xor(l0, 32, 64);
  float lq1 = l1 + __shfl_xor(l1, 32, 64);
  float* OS = (float*)smem;            // [128 q][67] f32 = 34304 B
  float* LS = (float*)(smem + 34304);  // [128 q] f32
  if (ksel == 1) {
    #pragma unroll
    for (int i = 0; i < 16; i++) {
      int eoff = (i & 3) + 8 * (i >> 2) + 4 * hi;
      OS[qr0 * 67 + eoff]      = oT00[i];
      OS[qr0 * 67 + 32 + eoff] = oT10[i];
      OS[qr1 * 67 + eoff]      = oT01[i];
      OS[qr1 * 67 + 32 + eoff] = oT11[i];
    }
    if (hi == 0) { LS[qr0] = lq0; LS[qr1] = lq1; }
  }
  __syncthreads();
  if (ksel == 0) {
    size_t tb = ((size_t)z * 12 + h) * 32 + qt;
    float la0 = lq0 + LS[qr0], la1 = lq1 + LS[qr1];
    if (hi == 0) { Lpart[tb * 128 + qr0] = la0; Lpart[tb * 128 + qr1] = la1; }
    bf16* ob0 = Opart + tb * 8192 + (size_t)qr0 * 64;
    bf16* ob1 = Opart + tb * 8192 + (size_t)qr1 * 64;
    #pragma unroll
    for (int g = 0; g < 4; g++) {
      int e0 = 8 * g + 4 * hi;
      bf16x4 a0, a1, b0, b1;
      #pragma unroll
      for (int r = 0; r < 4; r++) {
        a0[r] = (bf16)(oT00[g * 4 + r] + OS[qr0 * 67 + e0 + r]);
        a1[r] = (bf16)(oT10[g * 4 + r] + OS[qr0 * 67 + 32 + e0 + r]);
        b0[r] = (bf16)(oT01[g * 4 + r] + OS[qr1 * 67 + e0 + r]);
        b1[r] = (bf16)(oT11[g * 4 + r] + OS[qr1 * 67 + 32 + e0 + r]);
      }
      *(bf16x4*)(ob0 + e0)      = a0;
      *(bf16x4*)(ob0 + 32 + e0) = a1;
      *(bf16x4*)(ob1 + e0)      = b0;
      *(bf16x4*)(ob1 + 32 + e0) = b1;
    }
  }
}

// combine kv-split partials: o = (O0+O1)/(l0+l1); grid (32 qt, 12 h)
__global__ __launch_bounds__(256) void flash_combine_kernel(
    const bf16* __restrict__ Opart, const float* __restrict__ Lpart,
    bf16* __restrict__ o)
{
  int qt = blockIdx.x, h = blockIdx.y;
  int t = threadIdx.x;
  size_t t0 = (size_t)h * 32 + qt;
  size_t t1 = (size_t)(12 + h) * 32 + qt;
  #pragma unroll
  for (int qq = 0; qq < 2; qq++) {
    int q = qq * 64 + (t >> 2), eg = (t & 3) * 16;
    float inv = 1.0f / (Lpart[t0 * 128 + q] + Lpart[t1 * 128 + q]);
    const bf16* p0 = Opart + t0 * 8192 + (size_t)q * 64 + eg;
    const bf16* p1 = Opart + t1 * 8192 + (size_t)q * 64 + eg;
    bf16x8 a0 = *(const bf16x8*)p0, a1 = *(const bf16x8*)(p0 + 8);
    bf16x8 b0 = *(const bf16x8*)p1, b1 = *(const bf16x8*)(p1 + 8);
    bf16x8 r0, r1;
    #pragma unroll
    for (int i = 0; i < 8; i++) {
      r0[i] = (bf16)(((float)a0[i] + (float)b0[i]) * inv);
      r1[i] = (bf16)(((float)a1[i] + (float)b1[i]) * inv);
    }
    bf16* op = o + (size_t)(qt * 128 + q) * 768 + h * 64 + eg;
    *(bf16x8*)op       = r0;
    *(bf16x8*)(op + 8) = r1;
  }
}

extern "C" void kernel_launch(void* const* d_in, const int* in_sizes, int n_in,
                              void* d_out, int out_size, void* d_ws, size_t ws_size,
                              hipStream_t stream) {
  const float* x    = (const float*)d_in[0];
  const float* Wq   = (const float*)d_in[1];
  const float* bq   = (const float*)d_in[2];
  const float* Wk   = (const float*)d_in[3];
  const float* bk   = (const float*)d_in[4];
  const float* Wv   = (const float*)d_in[5];
  const float* bv   = (const float*)d_in[6];
  const float* Wo   = (const float*)d_in[7];
  const float* bo   = (const float*)d_in[8];
  const float* ln1w = (const float*)d_in[9];
  const float* ln1b = (const float*)d_in[10];
  const float* ln2w = (const float*)d_in[11];
  const float* ln2b = (const float*)d_in[12];
  const float* W1   = (const float*)d_in[13];
  const float* b1   = (const float*)d_in[14];
  const float* W2   = (const float*)d_in[15];
  const float* b2   = (const float*)d_in[16];
  float* out = (float*)d_out;

  // workspace layout (58,205,184 B):
  //  0         .. 25165824 : hbuf [4096][3072] bf16 (FFN1 out)
  //                          earlier: Lpart(0..393216) / ybuf(0..6291456, ln1)
  //                          qkbuf(6291456..18874368) / vtg(18874368..25165824)
  //                          opar_o(6291456..12582912, O-proj z=1 partial)
  //  25165824  .. 37748736 : x1 f32 [4096][768]; earlier Opart bf16 [2*12*32][128][64]
  //  37748736  .. 44040192 : obuf/y2buf bf16 [4096][768]; later FFN2 z=1 partial
  //  44040192  .. 58195968 : Wqkv_t | Wo_t | W1_t | W2_t (bf16)
  //  58195968  .. 58205184 : bqkv f32 [2304]
  char* ws = (char*)d_ws;
  bf16*  hbuf   = (bf16*)(ws + 0);
  float* Lpart  = (float*)(ws + 0);
  bf16*  ybuf   = (bf16*)(ws + 0);
  bf16*  qkbuf  = (bf16*)(ws + 6291456);
  bf16*  opar_o = (bf16*)(ws + 6291456);
  bf16*  vtg    = (bf16*)(ws + 18874368);
  float* x1     = (float*)(ws + 25165824);
  bf16*  Opart  = (bf16*)(ws + 25165824);
  bf16*  obuf   = (bf16*)(ws + 37748736);
  bf16*  y2buf  = obuf;
  bf16*  opar_f = obuf;                      // FFN2 z=1 partial (y2 dead)
  bf16*  Wqkv_t = (bf16*)(ws + 44040192);
  bf16*  Wo_t   = (bf16*)(ws + 47579136);
  bf16*  W1_t   = (bf16*)(ws + 48758784);
  bf16*  W2_t   = (bf16*)(ws + 53477376);
  float* bqkv   = (float*)(ws + 58195968);

  // 0) fused prep: LN1 + all weight conversions + qkv bias
  prep_kernel<<<11017, 256, 0, stream>>>(x, ln1w, ln1b, Wq, Wk, Wv, Wo, W1, W2,
                                         bq, bk, bv,
                                         ybuf, Wqkv_t, Wo_t, W1_t, W2_t, bqkv);
  // 2) qk | v^T = y @ Wqkv + bqkv   (round-3 grid; T1 swizzle inside)
  gemm_bt<4><<<dim3(18, 32), 256, 0, stream>>>(ybuf, Wqkv_t, bqkv,
                                               (const float*)nullptr, qkbuf, vtg,
                                               4096, 2304, 768);
  // 3) flash attention partials + combine -> obuf [4096][768]
  flash_kernel<<<dim3(32, 12, 2), 256, 0, stream>>>(qkbuf, vtg, Opart, Lpart);
  flash_combine_kernel<<<dim3(32, 12), 256, 0, stream>>>(Opart, Lpart, obuf);
  // 4) x1 = x + obuf @ Wo + bo  (split-K x2, bf16 partial; reduce fused in LN2)
  gemm_bt<5><<<dim3(6, 32, 2), 256, 0, stream>>>(obuf, Wo_t, bo, x, x1, opar_o,
                                                 4096, 768, 768);
  // 5) x1 += opar_o; y2 = LN2(x1)   (fused)
  ln_add_kernel<<<4096, 256, 0, stream>>>(x1, opar_o, ln2w, ln2b, y2buf);
  // 6) h = gelu(y2 @ W1 + b1)   (fast erf)
  gemm_bt<2><<<dim3(24, 32), 256, 0, stream>>>(y2buf, W1_t, b1,
                                               (const float*)nullptr, hbuf, nullptr,
                                               4096, 3072, 768);
  // 7) out = x1 + h @ W2 + b2  (split-K x2, round-3 config)
  gemm_bt<5><<<dim3(6, 32, 2), 256, 0, stream>>>(hbuf, W2_t, b2, x1, out, opar_f,
                                                 4096, 768, 3072);
  reduce_add_kernel<<<3072, 256, 0, stream>>>(out, opar_f);
}